// Round 1
// baseline (715.153 us; speedup 1.0000x reference)
//
#include <hip/hip_runtime.h>
#include <math.h>

#define NN 6000
#define NE 12000
// HC=128, H=4, D=32

__device__ __forceinline__ float gelu_f(float x) {
    return 0.5f * x * (1.0f + erff(x * 0.70710678118654752f));
}

__device__ __forceinline__ void atomicMaxF(float* addr, float v) {
    int cur = __float_as_int(*addr);
    while (__int_as_float(cur) < v) {
        int old = atomicCAS((int*)addr, cur, __float_as_int(v));
        if (old == cur) break;
        cur = old;
    }
}

// ---------------- precompute: Bmat[i][k][768] = [M0|M1|M2|M3|M4|root] ----------------
// M_j[k][o] = sum_ke enc5[j][ke] * nn_w[i][ke][k*128+o]   (+ nn_b for j==4)
__global__ __launch_bounds__(256) void k_pre_bmat(
    const float* __restrict__ nn_w, const float* __restrict__ nn_b,
    const float* __restrict__ nn_root,
    const float* __restrict__ eew, const float* __restrict__ eeb,
    float* __restrict__ Bmat)
{
    __shared__ float enc[5][128];
    int tid = threadIdx.x;
    for (int l = tid; l < 640; l += 256) {
        int j = l >> 7, k = l & 127;
        enc[j][k] = (j < 4) ? eew[j * 128 + k] : eeb[k];
    }
    __syncthreads();
    int gid = blockIdx.x * 256 + tid;       // 8 * 16384 total
    int i = gid >> 14;
    int col = gid & 16383;                  // k_in*128 + o
    int k_in = col >> 7, o = col & 127;
    const float* w = nn_w + (size_t)i * (128 * 16384) + col;
    float a0 = 0.f, a1 = 0.f, a2 = 0.f, a3 = 0.f, a4 = 0.f;
    #pragma unroll 8
    for (int k = 0; k < 128; ++k) {
        float wv = w[(size_t)k * 16384];
        a0 += enc[0][k] * wv; a1 += enc[1][k] * wv; a2 += enc[2][k] * wv;
        a3 += enc[3][k] * wv; a4 += enc[4][k] * wv;
    }
    a4 += nn_b[i * 16384 + col];
    float* brow = Bmat + (size_t)(i * 128 + k_in) * 768;
    brow[0 * 128 + o] = a0; brow[1 * 128 + o] = a1; brow[2 * 128 + o] = a2;
    brow[3 * 128 + o] = a3; brow[4 * 128 + o] = a4;
    brow[640 + o] = nn_root[i * 16384 + col];
}

// EW[i][j][o] = sum_k enc5[j][k] * gat_lin_e_w[i][k][o]
__global__ void k_pre_ew(const float* __restrict__ gat_e_w,
    const float* __restrict__ eew, const float* __restrict__ eeb,
    float* __restrict__ EW)
{
    int idx = blockIdx.x * 256 + threadIdx.x;
    if (idx >= 2 * 5 * 128) return;
    int i = idx / 640; int r = idx % 640; int j = r >> 7; int o = r & 127;
    float s = 0.f;
    for (int k = 0; k < 128; ++k) {
        float e = (j < 4) ? eew[j * 128 + k] : eeb[k];
        s += e * gat_e_w[i * 16384 + k * 128 + o];
    }
    EW[idx] = s;
}

__global__ void k_node_enc(const float* __restrict__ x,
    const float* __restrict__ w, float* __restrict__ h0)
{
    int idx = blockIdx.x * 256 + threadIdx.x;   // N*128
    int n = idx >> 7, c = idx & 127;
    float s = 0.f;
    #pragma unroll
    for (int f = 0; f < 6; ++f) s += x[n * 6 + f] * w[f * 128 + c];
    h0[idx] = s;
}

__global__ void k_init(float* __restrict__ agg, float* __restrict__ m, float* __restrict__ s)
{
    int idx = blockIdx.x * 256 + threadIdx.x;   // N*128
    agg[idx] = 0.f;
    if (idx < NN * 4) { m[idx] = -1e30f; s[idx] = 0.f; }
}

// C[r][c] = sum_k A[r][k]*B[k][c] + bias[c];  A:[nrows,128], B:[128,P] row-major
__global__ __launch_bounds__(256) void k_matmul(
    const float* __restrict__ A, const float* __restrict__ B,
    const float* __restrict__ bias, float* __restrict__ C,
    int nrows, int P)
{
    __shared__ __align__(16) float As[64][65];
    __shared__ __align__(16) float Bs[64][64];
    int r0 = blockIdx.x * 64;
    int c0 = blockIdx.y * 64;
    int tid = threadIdx.x;
    int tx = tid & 15, ty = tid >> 4;
    float acc[4][4] = {};
    for (int ks = 0; ks < 128; ks += 64) {
        for (int l = tid; l < 64 * 64; l += 256) {
            int rr = l >> 6, kk = l & 63;
            int r = r0 + rr;
            As[rr][kk] = (r < nrows) ? A[r * 128 + ks + kk] : 0.f;
        }
        for (int l = tid; l < 64 * 64; l += 256) {
            int kk = l >> 6, cc = l & 63;
            Bs[kk][cc] = B[(ks + kk) * P + c0 + cc];
        }
        __syncthreads();
        #pragma unroll 8
        for (int k = 0; k < 64; ++k) {
            float4 b4 = *(const float4*)&Bs[k][tx * 4];
            float a0 = As[ty * 4 + 0][k];
            float a1 = As[ty * 4 + 1][k];
            float a2 = As[ty * 4 + 2][k];
            float a3 = As[ty * 4 + 3][k];
            acc[0][0] += a0 * b4.x; acc[0][1] += a0 * b4.y; acc[0][2] += a0 * b4.z; acc[0][3] += a0 * b4.w;
            acc[1][0] += a1 * b4.x; acc[1][1] += a1 * b4.y; acc[1][2] += a1 * b4.z; acc[1][3] += a1 * b4.w;
            acc[2][0] += a2 * b4.x; acc[2][1] += a2 * b4.y; acc[2][2] += a2 * b4.z; acc[2][3] += a2 * b4.w;
            acc[3][0] += a3 * b4.x; acc[3][1] += a3 * b4.y; acc[3][2] += a3 * b4.z; acc[3][3] += a3 * b4.w;
        }
        __syncthreads();
    }
    float bv0 = 0.f, bv1 = 0.f, bv2 = 0.f, bv3 = 0.f;
    if (bias) {
        bv0 = bias[c0 + tx * 4 + 0]; bv1 = bias[c0 + tx * 4 + 1];
        bv2 = bias[c0 + tx * 4 + 2]; bv3 = bias[c0 + tx * 4 + 3];
    }
    #pragma unroll
    for (int m = 0; m < 4; ++m) {
        int r = r0 + ty * 4 + m;
        if (r < nrows) {
            float* crow = C + (size_t)r * P + c0 + tx * 4;
            crow[0] = acc[m][0] + bv0; crow[1] = acc[m][1] + bv1;
            crow[2] = acc[m][2] + bv2; crow[3] = acc[m][3] + bv3;
        }
    }
}

// GATv2 stage 1: logits + segment-max
__global__ __launch_bounds__(256) void k_gat_edge1(
    const float* __restrict__ XL, const float* __restrict__ XR,
    const int* __restrict__ ei, const float* __restrict__ eattr,
    const float* __restrict__ EW, const float* __restrict__ att,
    float* __restrict__ logits, float* __restrict__ m)
{
    int idx = blockIdx.x * 256 + threadIdx.x;   // E*128
    int e = idx >> 7, c = idx & 127;
    int s = ei[e], d = ei[NE + e];
    float a0 = eattr[e * 4 + 0], a1 = eattr[e * 4 + 1];
    float a2 = eattr[e * 4 + 2], a3 = eattr[e * 4 + 3];
    float xe = a0 * EW[c] + a1 * EW[128 + c] + a2 * EW[256 + c] + a3 * EW[384 + c] + EW[512 + c];
    float g = XL[s * 128 + c] + XR[d * 128 + c] + xe;
    g = (g > 0.f) ? g : 0.1f * g;
    float v = g * att[c];
    for (int o = 16; o > 0; o >>= 1) v += __shfl_xor(v, o, 32);
    if ((c & 31) == 0) {
        int h = c >> 5;
        logits[e * 4 + h] = v;
        atomicMaxF(&m[d * 4 + h], v);
    }
}

// GATv2 stage 2: exp + segment-sum
__global__ void k_gat_edge2(const int* __restrict__ ei, float* __restrict__ logits,
    const float* __restrict__ m, float* __restrict__ s)
{
    int idx = blockIdx.x * 256 + threadIdx.x;
    if (idx >= NE * 4) return;
    int e = idx >> 2, h = idx & 3;
    int d = ei[NE + e];
    float ex = expf(logits[idx] - m[d * 4 + h]);
    logits[idx] = ex;
    atomicAdd(&s[d * 4 + h], ex);
}

// GATv2 stage 3: weighted scatter of XL[src]
__global__ __launch_bounds__(256) void k_gat_edge3(
    const float* __restrict__ XL, const int* __restrict__ ei,
    const float* __restrict__ ex, const float* __restrict__ s,
    float* __restrict__ x1)
{
    int idx = blockIdx.x * 256 + threadIdx.x;   // E*128
    int e = idx >> 7, c = idx & 127;
    int sr = ei[e], d = ei[NE + e];
    int h = c >> 5;
    float alpha = ex[e * 4 + h] / (s[d * 4 + h] + 1e-16f);
    atomicAdd(&x1[d * 128 + c], alpha * XL[sr * 128 + c]);
}

// GAT post: h0 = gelu(ln(h0 + x1 + bias)); reset x1/m/s for next use
__global__ __launch_bounds__(256) void k_ln_gat(
    float* __restrict__ h0, float* __restrict__ x1,
    const float* __restrict__ bias, const float* __restrict__ g,
    const float* __restrict__ b, float* __restrict__ m, float* __restrict__ s)
{
    int row = blockIdx.x * 4 + (threadIdx.x >> 6);
    int lane = threadIdx.x & 63;
    if (row >= NN) return;
    float v0 = h0[row * 128 + lane]      + x1[row * 128 + lane]      + bias[lane];
    float v1 = h0[row * 128 + lane + 64] + x1[row * 128 + lane + 64] + bias[lane + 64];
    float sum = v0 + v1;
    for (int o = 32; o; o >>= 1) sum += __shfl_xor(sum, o, 64);
    float mean = sum * 0.0078125f;
    float d0 = v0 - mean, d1 = v1 - mean;
    float var = d0 * d0 + d1 * d1;
    for (int o = 32; o; o >>= 1) var += __shfl_xor(var, o, 64);
    float inv = rsqrtf(var * 0.0078125f + 1e-5f);
    h0[row * 128 + lane]      = gelu_f(d0 * inv * g[lane] + b[lane]);
    h0[row * 128 + lane + 64] = gelu_f(d1 * inv * g[lane + 64] + b[lane + 64]);
    x1[row * 128 + lane] = 0.f; x1[row * 128 + lane + 64] = 0.f;
    if (lane < 4) { m[row * 4 + lane] = -1e30f; s[row * 4 + lane] = 0.f; }
}

// decoder pre: hin = h0 + h; t = gelu(ln(hin))
__global__ __launch_bounds__(256) void k_ln_dec(
    const float* __restrict__ h0, const float* __restrict__ h,
    const float* __restrict__ g, const float* __restrict__ b,
    float* __restrict__ hin, float* __restrict__ t)
{
    int row = blockIdx.x * 4 + (threadIdx.x >> 6);
    int lane = threadIdx.x & 63;
    if (row >= NN) return;
    float v0 = h0[row * 128 + lane]      + h[row * 128 + lane];
    float v1 = h0[row * 128 + lane + 64] + h[row * 128 + lane + 64];
    hin[row * 128 + lane] = v0; hin[row * 128 + lane + 64] = v1;
    float sum = v0 + v1;
    for (int o = 32; o; o >>= 1) sum += __shfl_xor(sum, o, 64);
    float mean = sum * 0.0078125f;
    float d0 = v0 - mean, d1 = v1 - mean;
    float var = d0 * d0 + d1 * d1;
    for (int o = 32; o; o >>= 1) var += __shfl_xor(var, o, 64);
    float inv = rsqrtf(var * 0.0078125f + 1e-5f);
    t[row * 128 + lane]      = gelu_f(d0 * inv * g[lane] + b[lane]);
    t[row * 128 + lane + 64] = gelu_f(d1 * inv * g[lane + 64] + b[lane + 64]);
}

// conv message scatter: msg = sum_j a5_j * T_j[src], into agg[dst]
__global__ __launch_bounds__(256) void k_conv_edge(
    const float* __restrict__ TR, const int* __restrict__ ei,
    const float* __restrict__ eattr, float* __restrict__ agg)
{
    int idx = blockIdx.x * 256 + threadIdx.x;   // E*128
    int e = idx >> 7, c = idx & 127;
    int s = ei[e], d = ei[NE + e];
    float a0 = eattr[e * 4 + 0], a1 = eattr[e * 4 + 1];
    float a2 = eattr[e * 4 + 2], a3 = eattr[e * 4 + 3];
    const float* trb = TR + (size_t)s * 768;
    float msg = a0 * trb[c] + a1 * trb[128 + c] + a2 * trb[256 + c]
              + a3 * trb[384 + c] + trb[512 + c];
    atomicAdd(&agg[d * 128 + c], msg);
}

// conv combine: h = (hin) + agg + root-term + bias; re-zero agg
__global__ void k_combine(const float* __restrict__ TR, float* __restrict__ agg,
    const float* __restrict__ hin, const float* __restrict__ bias,
    float* __restrict__ h)
{
    int idx = blockIdx.x * 256 + threadIdx.x;   // N*128
    int n = idx >> 7, c = idx & 127;
    float v = agg[idx] + TR[(size_t)n * 768 + 640 + c] + bias[c];
    if (hin) v += hin[idx];
    h[idx] = v;
    agg[idx] = 0.f;
}

// final: out = gelu(ln(h)) @ out_w + out_b
__global__ __launch_bounds__(256) void k_final(
    const float* __restrict__ h, const float* __restrict__ g,
    const float* __restrict__ b, const float* __restrict__ W,
    const float* __restrict__ ob, float* __restrict__ out)
{
    int row = blockIdx.x * 4 + (threadIdx.x >> 6);
    int lane = threadIdx.x & 63;
    if (row >= NN) return;
    float v0 = h[row * 128 + lane], v1 = h[row * 128 + lane + 64];
    float sum = v0 + v1;
    for (int o = 32; o; o >>= 1) sum += __shfl_xor(sum, o, 64);
    float mean = sum * 0.0078125f;
    float d0 = v0 - mean, d1 = v1 - mean;
    float var = d0 * d0 + d1 * d1;
    for (int o = 32; o; o >>= 1) var += __shfl_xor(var, o, 64);
    float inv = rsqrtf(var * 0.0078125f + 1e-5f);
    float y0 = gelu_f(d0 * inv * g[lane] + b[lane]);
    float y1 = gelu_f(d1 * inv * g[lane + 64] + b[lane + 64]);
    float p0 = y0 * W[lane * 2 + 0] + y1 * W[(lane + 64) * 2 + 0];
    float p1 = y0 * W[lane * 2 + 1] + y1 * W[(lane + 64) * 2 + 1];
    for (int o = 32; o; o >>= 1) {
        p0 += __shfl_xor(p0, o, 64);
        p1 += __shfl_xor(p1, o, 64);
    }
    if (lane == 0) {
        out[row * 2 + 0] = p0 + ob[0];
        out[row * 2 + 1] = p1 + ob[1];
    }
}

extern "C" void kernel_launch(void* const* d_in, const int* in_sizes, int n_in,
                              void* d_out, int out_size, void* d_ws, size_t ws_size,
                              hipStream_t stream)
{
    const float* x        = (const float*)d_in[0];
    const int*   ei       = (const int*)d_in[1];
    const float* eattr    = (const float*)d_in[2];
    const float* node_w   = (const float*)d_in[4];
    const float* eew      = (const float*)d_in[5];
    const float* eeb      = (const float*)d_in[6];
    const float* gat_l_w  = (const float*)d_in[7];
    const float* gat_l_b  = (const float*)d_in[8];
    const float* gat_r_w  = (const float*)d_in[9];
    const float* gat_r_b  = (const float*)d_in[10];
    const float* gat_e_w  = (const float*)d_in[11];
    const float* gat_att  = (const float*)d_in[12];
    const float* gat_bias = (const float*)d_in[13];
    const float* gat_ln_g = (const float*)d_in[14];
    const float* gat_ln_b = (const float*)d_in[15];
    const float* nn_w     = (const float*)d_in[16];
    const float* nn_b     = (const float*)d_in[17];
    const float* nn_root  = (const float*)d_in[18];
    const float* nn_bias  = (const float*)d_in[19];
    const float* dec_g    = (const float*)d_in[20];
    const float* dec_b    = (const float*)d_in[21];
    const float* out_w    = (const float*)d_in[22];
    const float* out_b    = (const float*)d_in[23];
    float* out = (float*)d_out;

    float* ws   = (float*)d_ws;
    float* BMAT = ws;                   // 8*128*768 = 786432
    float* EW   = BMAT + 786432;        // 1280
    float* H0   = EW + 1280;            // 768000
    float* H    = H0 + 768000;
    float* HIN  = H + 768000;
    float* T    = HIN + 768000;
    float* TR   = T + 768000;           // 4608000
    float* AGG  = TR + 4608000;         // 768000 (doubles as GAT x1)
    float* XL   = AGG + 768000;
    float* XR   = XL + 768000;
    float* LOG  = XR + 768000;          // 48000
    float* M    = LOG + 48000;          // 24000
    float* S    = M + 24000;            // 24000

    dim3 b256(256);
    hipLaunchKernelGGL(k_pre_bmat, dim3(512), b256, 0, stream, nn_w, nn_b, nn_root, eew, eeb, BMAT);
    hipLaunchKernelGGL(k_pre_ew, dim3(5), b256, 0, stream, gat_e_w, eew, eeb, EW);
    hipLaunchKernelGGL(k_node_enc, dim3(3000), b256, 0, stream, x, node_w, H0);
    hipLaunchKernelGGL(k_init, dim3(3000), b256, 0, stream, AGG, M, S);

    for (int i = 0; i < 2; ++i) {
        hipLaunchKernelGGL(k_matmul, dim3(94, 2), b256, 0, stream,
                           H0, gat_l_w + i * 16384, gat_l_b + i * 128, XL, NN, 128);
        hipLaunchKernelGGL(k_matmul, dim3(94, 2), b256, 0, stream,
                           H0, gat_r_w + i * 16384, gat_r_b + i * 128, XR, NN, 128);
        hipLaunchKernelGGL(k_gat_edge1, dim3(6000), b256, 0, stream,
                           XL, XR, ei, eattr, EW + i * 640, gat_att + i * 128, LOG, M);
        hipLaunchKernelGGL(k_gat_edge2, dim3(188), b256, 0, stream, ei, LOG, M, S);
        hipLaunchKernelGGL(k_gat_edge3, dim3(6000), b256, 0, stream, XL, ei, LOG, S, AGG);
        hipLaunchKernelGGL(k_ln_gat, dim3(1500), b256, 0, stream,
                           H0, AGG, gat_bias + i * 128, gat_ln_g + i * 128, gat_ln_b + i * 128, M, S);
    }

    // initial conv: input h0, layer-0 weights
    hipLaunchKernelGGL(k_matmul, dim3(94, 12), b256, 0, stream,
                       H0, BMAT, (const float*)nullptr, TR, NN, 768);
    hipLaunchKernelGGL(k_conv_edge, dim3(6000), b256, 0, stream, TR, ei, eattr, AGG);
    hipLaunchKernelGGL(k_combine, dim3(3000), b256, 0, stream,
                       TR, AGG, (const float*)nullptr, nn_bias, H);

    for (int i = 0; i < 8; ++i) {
        hipLaunchKernelGGL(k_ln_dec, dim3(1500), b256, 0, stream,
                           H0, H, dec_g + i * 128, dec_b + i * 128, HIN, T);
        hipLaunchKernelGGL(k_matmul, dim3(94, 12), b256, 0, stream,
                           T, BMAT + (size_t)i * 98304, (const float*)nullptr, TR, NN, 768);
        hipLaunchKernelGGL(k_conv_edge, dim3(6000), b256, 0, stream, TR, ei, eattr, AGG);
        hipLaunchKernelGGL(k_combine, dim3(3000), b256, 0, stream,
                           TR, AGG, HIN, nn_bias + i * 128, H);
    }

    hipLaunchKernelGGL(k_final, dim3(1500), b256, 0, stream,
                       H, dec_g, dec_b, out_w, out_b, out);
}

// Round 2
// 477.624 us; speedup vs baseline: 1.4973x; 1.4973x over previous
//
#include <hip/hip_runtime.h>
#include <math.h>

#define NN 6000
#define NE 12000
// HC=128, H=4, D=32

typedef __bf16 bf16x8 __attribute__((ext_vector_type(8)));
typedef unsigned short u16x8 __attribute__((ext_vector_type(8)));
typedef float f32x4 __attribute__((ext_vector_type(4)));

__device__ __forceinline__ float gelu_f(float x) {
    return 0.5f * x * (1.0f + erff(x * 0.70710678118654752f));
}

__device__ __forceinline__ unsigned short bf16_rne(float x) {
    unsigned int u = __float_as_uint(x);
    unsigned int r = u + 0x7FFFu + ((u >> 16) & 1u);
    return (unsigned short)(r >> 16);
}
__device__ __forceinline__ float bf16_to_f(unsigned short h) {
    return __uint_as_float(((unsigned int)h) << 16);
}
__device__ __forceinline__ void split2(float x, unsigned short& hi, unsigned short& lo) {
    hi = bf16_rne(x);
    lo = bf16_rne(x - bf16_to_f(hi));
}

__device__ __forceinline__ void atomicMaxF(float* addr, float v) {
    int cur = __float_as_int(*addr);
    while (__int_as_float(cur) < v) {
        int old = atomicCAS((int*)addr, cur, __float_as_int(v));
        if (old == cur) break;
        cur = old;
    }
}

// ---------------- precompute: Bmat[i][k][768] = [M0|M1|M2|M3|M4|root] ----------------
__global__ __launch_bounds__(256) void k_pre_bmat(
    const float* __restrict__ nn_w, const float* __restrict__ nn_b,
    const float* __restrict__ nn_root,
    const float* __restrict__ eew, const float* __restrict__ eeb,
    float* __restrict__ Bmat)
{
    __shared__ float enc[5][128];
    int tid = threadIdx.x;
    for (int l = tid; l < 640; l += 256) {
        int j = l >> 7, k = l & 127;
        enc[j][k] = (j < 4) ? eew[j * 128 + k] : eeb[k];
    }
    __syncthreads();
    int gid = blockIdx.x * 256 + tid;       // 8 * 16384 total
    int i = gid >> 14;
    int col = gid & 16383;                  // k_in*128 + o
    int k_in = col >> 7, o = col & 127;
    const float* w = nn_w + (size_t)i * (128 * 16384) + col;
    float a0 = 0.f, a1 = 0.f, a2 = 0.f, a3 = 0.f, a4 = 0.f;
    #pragma unroll 8
    for (int k = 0; k < 128; ++k) {
        float wv = w[(size_t)k * 16384];
        a0 += enc[0][k] * wv; a1 += enc[1][k] * wv; a2 += enc[2][k] * wv;
        a3 += enc[3][k] * wv; a4 += enc[4][k] * wv;
    }
    a4 += nn_b[i * 16384 + col];
    float* brow = Bmat + (size_t)(i * 128 + k_in) * 768;
    brow[0 * 128 + o] = a0; brow[1 * 128 + o] = a1; brow[2 * 128 + o] = a2;
    brow[3 * 128 + o] = a3; brow[4 * 128 + o] = a4;
    brow[640 + o] = nn_root[i * 16384 + col];
}

// transpose + bf16 hi/lo split: src f32 [nmat][128][P] -> dst [nmat][P][128]
// grid (nmat, P/128), block 256
__global__ __launch_bounds__(256) void k_split_t(
    const float* __restrict__ src, size_t mat_stride, int P,
    unsigned short* __restrict__ dhi, unsigned short* __restrict__ dlo)
{
    __shared__ float tile[128][129];
    int i = blockIdx.x, nb = blockIdx.y, tid = threadIdx.x;
    const float* s = src + (size_t)i * mat_stride + nb * 128;
    for (int l = tid; l < 128 * 128; l += 256) {
        int k = l >> 7, n = l & 127;
        tile[k][n] = s[(size_t)k * P + n];
    }
    __syncthreads();
    size_t dbase = ((size_t)i * P + (size_t)nb * 128) * 128;
    for (int l = tid; l < 128 * 128; l += 256) {
        int n = l >> 7, k = l & 127;
        float v = tile[k][n];
        unsigned short hi, lo; split2(v, hi, lo);
        dhi[dbase + (size_t)n * 128 + k] = hi;
        dlo[dbase + (size_t)n * 128 + k] = lo;
    }
}

// EW[i][j][o] = sum_k enc5[j][k] * gat_lin_e_w[i][k][o]
__global__ void k_pre_ew(const float* __restrict__ gat_e_w,
    const float* __restrict__ eew, const float* __restrict__ eeb,
    float* __restrict__ EW)
{
    int idx = blockIdx.x * 256 + threadIdx.x;
    if (idx >= 2 * 5 * 128) return;
    int i = idx / 640; int r = idx % 640; int j = r >> 7; int o = r & 127;
    float s = 0.f;
    for (int k = 0; k < 128; ++k) {
        float e = (j < 4) ? eew[j * 128 + k] : eeb[k];
        s += e * gat_e_w[i * 16384 + k * 128 + o];
    }
    EW[idx] = s;
}

__global__ void k_node_enc(const float* __restrict__ x,
    const float* __restrict__ w, float* __restrict__ h0,
    unsigned short* __restrict__ hh, unsigned short* __restrict__ hl)
{
    int idx = blockIdx.x * 256 + threadIdx.x;   // N*128
    int n = idx >> 7, c = idx & 127;
    float s = 0.f;
    #pragma unroll
    for (int f = 0; f < 6; ++f) s += x[n * 6 + f] * w[f * 128 + c];
    h0[idx] = s;
    unsigned short hi, lo; split2(s, hi, lo);
    hh[idx] = hi; hl[idx] = lo;
}

__global__ void k_init(float* __restrict__ agg, float* __restrict__ m, float* __restrict__ s)
{
    int idx = blockIdx.x * 256 + threadIdx.x;   // N*128
    agg[idx] = 0.f;
    if (idx < NN * 4) { m[idx] = -1e30f; s[idx] = 0.f; }
}

// ---------------- MFMA matmul: C[M,P] f32 = (Ahi+Alo) @ (Bhi+Blo)^T(stored [P][128]) + bias
// bf16x3 passes: hi*hi + hi*lo + lo*hi. grid (ceil(M/128), P/64), block 512.
__global__ __launch_bounds__(512) void k_mm_mfma(
    const unsigned short* __restrict__ Ah, const unsigned short* __restrict__ Al,
    const unsigned short* __restrict__ Bh, const unsigned short* __restrict__ Bl,
    const float* __restrict__ bias, float* __restrict__ C, int M, int P)
{
    __shared__ unsigned short sAh[128 * 128];
    __shared__ unsigned short sAl[128 * 128];
    __shared__ unsigned short sBh[64 * 128];
    __shared__ unsigned short sBl[64 * 128];
    const int tid = threadIdx.x;
    const int r0 = blockIdx.x * 128, n0 = blockIdx.y * 64;
    // stage A: 128 rows x 16 units(16B) per buffer; XOR-swizzle unit by row&7
    #pragma unroll
    for (int i = 0; i < 4; ++i) {
        int g = tid + i * 512; int row = g >> 4, u = g & 15;
        int r = r0 + row;
        int dst = row * 128 + ((u ^ (row & 7)) << 3);
        if (r < M) {
            *(u16x8*)&sAh[dst] = *(const u16x8*)&Ah[(size_t)r * 128 + u * 8];
            *(u16x8*)&sAl[dst] = *(const u16x8*)&Al[(size_t)r * 128 + u * 8];
        } else {
            u16x8 z; for (int j = 0; j < 8; ++j) z[j] = 0;
            *(u16x8*)&sAh[dst] = z; *(u16x8*)&sAl[dst] = z;
        }
    }
    // stage B: 64 rows (cols of C) x 16 units
    #pragma unroll
    for (int i = 0; i < 2; ++i) {
        int g = tid + i * 512; int row = g >> 4, u = g & 15;
        int dst = row * 128 + ((u ^ (row & 7)) << 3);
        size_t s = (size_t)(n0 + row) * 128 + u * 8;
        *(u16x8*)&sBh[dst] = *(const u16x8*)&Bh[s];
        *(u16x8*)&sBl[dst] = *(const u16x8*)&Bl[s];
    }
    __syncthreads();
    const int lane = tid & 63, wid = tid >> 6;
    const int wm = wid & 3, wn = wid >> 2;       // 4 row-groups x 2 col-groups
    const int l15 = lane & 15, lg = lane >> 4;
    f32x4 acc[2][2] = {};
    #pragma unroll
    for (int kk = 0; kk < 4; ++kk) {
        u16x8 ah[2], al[2], bh[2], bl[2];
        #pragma unroll
        for (int fm = 0; fm < 2; ++fm) {
            int row = wm * 32 + fm * 16 + l15;
            int off = row * 128 + ((((kk << 2) + lg) ^ (row & 7)) << 3);
            ah[fm] = *(const u16x8*)&sAh[off];
            al[fm] = *(const u16x8*)&sAl[off];
        }
        #pragma unroll
        for (int fn = 0; fn < 2; ++fn) {
            int row = wn * 32 + fn * 16 + l15;
            int off = row * 128 + ((((kk << 2) + lg) ^ (row & 7)) << 3);
            bh[fn] = *(const u16x8*)&sBh[off];
            bl[fn] = *(const u16x8*)&sBl[off];
        }
        #pragma unroll
        for (int fm = 0; fm < 2; ++fm)
        #pragma unroll
        for (int fn = 0; fn < 2; ++fn) {
            acc[fm][fn] = __builtin_amdgcn_mfma_f32_16x16x32_bf16(
                __builtin_bit_cast(bf16x8, ah[fm]), __builtin_bit_cast(bf16x8, bh[fn]),
                acc[fm][fn], 0, 0, 0);
            acc[fm][fn] = __builtin_amdgcn_mfma_f32_16x16x32_bf16(
                __builtin_bit_cast(bf16x8, ah[fm]), __builtin_bit_cast(bf16x8, bl[fn]),
                acc[fm][fn], 0, 0, 0);
            acc[fm][fn] = __builtin_amdgcn_mfma_f32_16x16x32_bf16(
                __builtin_bit_cast(bf16x8, al[fm]), __builtin_bit_cast(bf16x8, bh[fn]),
                acc[fm][fn], 0, 0, 0);
        }
    }
    // epilogue: C row = (lane>>4)*4 + reg, col = lane&15  [m89-verified]
    #pragma unroll
    for (int fn = 0; fn < 2; ++fn) {
        int col = n0 + wn * 32 + fn * 16 + l15;
        float bv = bias ? bias[col] : 0.f;
        #pragma unroll
        for (int fm = 0; fm < 2; ++fm) {
            int rbase = r0 + wm * 32 + fm * 16 + lg * 4;
            #pragma unroll
            for (int j = 0; j < 4; ++j) {
                int r = rbase + j;
                if (r < M) C[(size_t)r * P + col] = acc[fm][fn][j] + bv;
            }
        }
    }
}

// GATv2 stage 1: logits + segment-max
__global__ __launch_bounds__(256) void k_gat_edge1(
    const float* __restrict__ XL, const float* __restrict__ XR,
    const int* __restrict__ ei, const float* __restrict__ eattr,
    const float* __restrict__ EW, const float* __restrict__ att,
    float* __restrict__ logits, float* __restrict__ m)
{
    int idx = blockIdx.x * 256 + threadIdx.x;   // E*128
    int e = idx >> 7, c = idx & 127;
    int s = ei[e], d = ei[NE + e];
    float a0 = eattr[e * 4 + 0], a1 = eattr[e * 4 + 1];
    float a2 = eattr[e * 4 + 2], a3 = eattr[e * 4 + 3];
    float xe = a0 * EW[c] + a1 * EW[128 + c] + a2 * EW[256 + c] + a3 * EW[384 + c] + EW[512 + c];
    float g = XL[s * 128 + c] + XR[d * 128 + c] + xe;
    g = (g > 0.f) ? g : 0.1f * g;
    float v = g * att[c];
    for (int o = 16; o > 0; o >>= 1) v += __shfl_xor(v, o, 32);
    if ((c & 31) == 0) {
        int h = c >> 5;
        logits[e * 4 + h] = v;
        atomicMaxF(&m[d * 4 + h], v);
    }
}

// GATv2 stage 2: exp + segment-sum
__global__ void k_gat_edge2(const int* __restrict__ ei, float* __restrict__ logits,
    const float* __restrict__ m, float* __restrict__ s)
{
    int idx = blockIdx.x * 256 + threadIdx.x;
    if (idx >= NE * 4) return;
    int e = idx >> 2, h = idx & 3;
    int d = ei[NE + e];
    float ex = expf(logits[idx] - m[d * 4 + h]);
    logits[idx] = ex;
    atomicAdd(&s[d * 4 + h], ex);
}

// GATv2 stage 3: weighted scatter of XL[src]
__global__ __launch_bounds__(256) void k_gat_edge3(
    const float* __restrict__ XL, const int* __restrict__ ei,
    const float* __restrict__ ex, const float* __restrict__ s,
    float* __restrict__ x1)
{
    int idx = blockIdx.x * 256 + threadIdx.x;   // E*128
    int e = idx >> 7, c = idx & 127;
    int sr = ei[e], d = ei[NE + e];
    int h = c >> 5;
    float alpha = ex[e * 4 + h] / (s[d * 4 + h] + 1e-16f);
    atomicAdd(&x1[d * 128 + c], alpha * XL[sr * 128 + c]);
}

// GAT post: h0 = gelu(ln(h0 + x1 + bias)); emits bf16 hi/lo split; resets x1/m/s
__global__ __launch_bounds__(256) void k_ln_gat(
    float* __restrict__ h0, float* __restrict__ x1,
    const float* __restrict__ bias, const float* __restrict__ g,
    const float* __restrict__ b, float* __restrict__ m, float* __restrict__ s,
    unsigned short* __restrict__ hh, unsigned short* __restrict__ hl)
{
    int row = blockIdx.x * 4 + (threadIdx.x >> 6);
    int lane = threadIdx.x & 63;
    if (row >= NN) return;
    float v0 = h0[row * 128 + lane]      + x1[row * 128 + lane]      + bias[lane];
    float v1 = h0[row * 128 + lane + 64] + x1[row * 128 + lane + 64] + bias[lane + 64];
    float sum = v0 + v1;
    for (int o = 32; o; o >>= 1) sum += __shfl_xor(sum, o, 64);
    float mean = sum * 0.0078125f;
    float d0 = v0 - mean, d1 = v1 - mean;
    float var = d0 * d0 + d1 * d1;
    for (int o = 32; o; o >>= 1) var += __shfl_xor(var, o, 64);
    float inv = rsqrtf(var * 0.0078125f + 1e-5f);
    float y0 = gelu_f(d0 * inv * g[lane] + b[lane]);
    float y1 = gelu_f(d1 * inv * g[lane + 64] + b[lane + 64]);
    h0[row * 128 + lane] = y0; h0[row * 128 + lane + 64] = y1;
    unsigned short hi, lo;
    split2(y0, hi, lo); hh[row * 128 + lane] = hi;      hl[row * 128 + lane] = lo;
    split2(y1, hi, lo); hh[row * 128 + lane + 64] = hi; hl[row * 128 + lane + 64] = lo;
    x1[row * 128 + lane] = 0.f; x1[row * 128 + lane + 64] = 0.f;
    if (lane < 4) { m[row * 4 + lane] = -1e30f; s[row * 4 + lane] = 0.f; }
}

// decoder pre: hin = h0 + h; t = gelu(ln(hin)) emitted as bf16 hi/lo
__global__ __launch_bounds__(256) void k_ln_dec(
    const float* __restrict__ h0, const float* __restrict__ h,
    const float* __restrict__ g, const float* __restrict__ b,
    float* __restrict__ hin,
    unsigned short* __restrict__ th, unsigned short* __restrict__ tl)
{
    int row = blockIdx.x * 4 + (threadIdx.x >> 6);
    int lane = threadIdx.x & 63;
    if (row >= NN) return;
    float v0 = h0[row * 128 + lane]      + h[row * 128 + lane];
    float v1 = h0[row * 128 + lane + 64] + h[row * 128 + lane + 64];
    hin[row * 128 + lane] = v0; hin[row * 128 + lane + 64] = v1;
    float sum = v0 + v1;
    for (int o = 32; o; o >>= 1) sum += __shfl_xor(sum, o, 64);
    float mean = sum * 0.0078125f;
    float d0 = v0 - mean, d1 = v1 - mean;
    float var = d0 * d0 + d1 * d1;
    for (int o = 32; o; o >>= 1) var += __shfl_xor(var, o, 64);
    float inv = rsqrtf(var * 0.0078125f + 1e-5f);
    float y0 = gelu_f(d0 * inv * g[lane] + b[lane]);
    float y1 = gelu_f(d1 * inv * g[lane + 64] + b[lane + 64]);
    unsigned short hi, lo;
    split2(y0, hi, lo); th[row * 128 + lane] = hi;      tl[row * 128 + lane] = lo;
    split2(y1, hi, lo); th[row * 128 + lane + 64] = hi; tl[row * 128 + lane + 64] = lo;
}

// conv message scatter: msg = sum_j a5_j * T_j[src], into agg[dst]
__global__ __launch_bounds__(256) void k_conv_edge(
    const float* __restrict__ TR, const int* __restrict__ ei,
    const float* __restrict__ eattr, float* __restrict__ agg)
{
    int idx = blockIdx.x * 256 + threadIdx.x;   // E*128
    int e = idx >> 7, c = idx & 127;
    int s = ei[e], d = ei[NE + e];
    float a0 = eattr[e * 4 + 0], a1 = eattr[e * 4 + 1];
    float a2 = eattr[e * 4 + 2], a3 = eattr[e * 4 + 3];
    const float* trb = TR + (size_t)s * 768;
    float msg = a0 * trb[c] + a1 * trb[128 + c] + a2 * trb[256 + c]
              + a3 * trb[384 + c] + trb[512 + c];
    atomicAdd(&agg[d * 128 + c], msg);
}

// conv combine: h = (hin) + agg + root-term + bias; re-zero agg
__global__ void k_combine(const float* __restrict__ TR, float* __restrict__ agg,
    const float* __restrict__ hin, const float* __restrict__ bias,
    float* __restrict__ h)
{
    int idx = blockIdx.x * 256 + threadIdx.x;   // N*128
    int n = idx >> 7, c = idx & 127;
    float v = agg[idx] + TR[(size_t)n * 768 + 640 + c] + bias[c];
    if (hin) v += hin[idx];
    h[idx] = v;
    agg[idx] = 0.f;
}

// final: out = gelu(ln(h)) @ out_w + out_b
__global__ __launch_bounds__(256) void k_final(
    const float* __restrict__ h, const float* __restrict__ g,
    const float* __restrict__ b, const float* __restrict__ W,
    const float* __restrict__ ob, float* __restrict__ out)
{
    int row = blockIdx.x * 4 + (threadIdx.x >> 6);
    int lane = threadIdx.x & 63;
    if (row >= NN) return;
    float v0 = h[row * 128 + lane], v1 = h[row * 128 + lane + 64];
    float sum = v0 + v1;
    for (int o = 32; o; o >>= 1) sum += __shfl_xor(sum, o, 64);
    float mean = sum * 0.0078125f;
    float d0 = v0 - mean, d1 = v1 - mean;
    float var = d0 * d0 + d1 * d1;
    for (int o = 32; o; o >>= 1) var += __shfl_xor(var, o, 64);
    float inv = rsqrtf(var * 0.0078125f + 1e-5f);
    float y0 = gelu_f(d0 * inv * g[lane] + b[lane]);
    float y1 = gelu_f(d1 * inv * g[lane + 64] + b[lane + 64]);
    float p0 = y0 * W[lane * 2 + 0] + y1 * W[(lane + 64) * 2 + 0];
    float p1 = y0 * W[lane * 2 + 1] + y1 * W[(lane + 64) * 2 + 1];
    for (int o = 32; o; o >>= 1) {
        p0 += __shfl_xor(p0, o, 64);
        p1 += __shfl_xor(p1, o, 64);
    }
    if (lane == 0) {
        out[row * 2 + 0] = p0 + ob[0];
        out[row * 2 + 1] = p1 + ob[1];
    }
}

extern "C" void kernel_launch(void* const* d_in, const int* in_sizes, int n_in,
                              void* d_out, int out_size, void* d_ws, size_t ws_size,
                              hipStream_t stream)
{
    const float* x        = (const float*)d_in[0];
    const int*   ei       = (const int*)d_in[1];
    const float* eattr    = (const float*)d_in[2];
    const float* node_w   = (const float*)d_in[4];
    const float* eew      = (const float*)d_in[5];
    const float* eeb      = (const float*)d_in[6];
    const float* gat_l_w  = (const float*)d_in[7];
    const float* gat_l_b  = (const float*)d_in[8];
    const float* gat_r_w  = (const float*)d_in[9];
    const float* gat_r_b  = (const float*)d_in[10];
    const float* gat_e_w  = (const float*)d_in[11];
    const float* gat_att  = (const float*)d_in[12];
    const float* gat_bias = (const float*)d_in[13];
    const float* gat_ln_g = (const float*)d_in[14];
    const float* gat_ln_b = (const float*)d_in[15];
    const float* nn_w     = (const float*)d_in[16];
    const float* nn_b     = (const float*)d_in[17];
    const float* nn_root  = (const float*)d_in[18];
    const float* nn_bias  = (const float*)d_in[19];
    const float* dec_g    = (const float*)d_in[20];
    const float* dec_b    = (const float*)d_in[21];
    const float* out_w    = (const float*)d_in[22];
    const float* out_b    = (const float*)d_in[23];
    float* out = (float*)d_out;

    float* ws   = (float*)d_ws;
    float* BMAT = ws;                   // 8*128*768
    float* EW   = BMAT + 786432;        // 1280
    float* H0   = EW + 1280;            // 768000
    float* H    = H0 + 768000;
    float* HIN  = H + 768000;
    float* TR   = HIN + 768000;         // 4608000 (6000x768)
    float* AGG  = TR + 4608000;         // 768000 (doubles as GAT x1)
    float* XL   = AGG + 768000;
    float* XR   = XL + 768000;
    float* LOG  = XR + 768000;          // 48000
    float* MX   = LOG + 48000;          // 24000
    float* SX   = MX + 24000;           // 24000
    unsigned short* usbase = (unsigned short*)(SX + 24000);
    unsigned short* BThi = usbase;              // 8*768*128
    unsigned short* BTlo = BThi + 786432;
    unsigned short* WThi = BTlo + 786432;       // 4 mats x 128x128 (l0,l1,r0,r1)
    unsigned short* WTlo = WThi + 65536;
    unsigned short* H0h  = WTlo + 65536;        // 768000
    unsigned short* H0l  = H0h + 768000;
    // T hi/lo alias XL/XR (GAT-phase only buffers), exactly 768000 floats = 1.536M ushorts
    unsigned short* Th   = (unsigned short*)XL;
    unsigned short* Tl   = Th + 768000;

    dim3 b256(256), b512(512);
    hipLaunchKernelGGL(k_pre_bmat, dim3(512), b256, 0, stream, nn_w, nn_b, nn_root, eew, eeb, BMAT);
    hipLaunchKernelGGL(k_split_t, dim3(8, 6), b256, 0, stream, BMAT, (size_t)98304, 768, BThi, BTlo);
    hipLaunchKernelGGL(k_split_t, dim3(2, 1), b256, 0, stream, gat_l_w, (size_t)16384, 128, WThi, WTlo);
    hipLaunchKernelGGL(k_split_t, dim3(2, 1), b256, 0, stream, gat_r_w, (size_t)16384, 128, WThi + 32768, WTlo + 32768);
    hipLaunchKernelGGL(k_pre_ew, dim3(5), b256, 0, stream, gat_e_w, eew, eeb, EW);
    hipLaunchKernelGGL(k_node_enc, dim3(3000), b256, 0, stream, x, node_w, H0, H0h, H0l);
    hipLaunchKernelGGL(k_init, dim3(3000), b256, 0, stream, AGG, MX, SX);

    for (int i = 0; i < 2; ++i) {
        hipLaunchKernelGGL(k_mm_mfma, dim3(47, 2), b512, 0, stream,
                           H0h, H0l, WThi + i * 16384, WTlo + i * 16384,
                           gat_l_b + i * 128, XL, NN, 128);
        hipLaunchKernelGGL(k_mm_mfma, dim3(47, 2), b512, 0, stream,
                           H0h, H0l, WThi + 32768 + i * 16384, WTlo + 32768 + i * 16384,
                           gat_r_b + i * 128, XR, NN, 128);
        hipLaunchKernelGGL(k_gat_edge1, dim3(6000), b256, 0, stream,
                           XL, XR, ei, eattr, EW + i * 640, gat_att + i * 128, LOG, MX);
        hipLaunchKernelGGL(k_gat_edge2, dim3(188), b256, 0, stream, ei, LOG, MX, SX);
        hipLaunchKernelGGL(k_gat_edge3, dim3(6000), b256, 0, stream, XL, ei, LOG, SX, AGG);
        hipLaunchKernelGGL(k_ln_gat, dim3(1500), b256, 0, stream,
                           H0, AGG, gat_bias + i * 128, gat_ln_g + i * 128, gat_ln_b + i * 128,
                           MX, SX, H0h, H0l);
    }

    // initial conv: input h0 (post-GAT), layer-0 weights
    hipLaunchKernelGGL(k_mm_mfma, dim3(47, 12), b512, 0, stream,
                       H0h, H0l, BThi, BTlo, (const float*)nullptr, TR, NN, 768);
    hipLaunchKernelGGL(k_conv_edge, dim3(6000), b256, 0, stream, TR, ei, eattr, AGG);
    hipLaunchKernelGGL(k_combine, dim3(3000), b256, 0, stream,
                       TR, AGG, (const float*)nullptr, nn_bias, H);

    for (int i = 0; i < 8; ++i) {
        hipLaunchKernelGGL(k_ln_dec, dim3(1500), b256, 0, stream,
                           H0, H, dec_g + i * 128, dec_b + i * 128, HIN, Th, Tl);
        hipLaunchKernelGGL(k_mm_mfma, dim3(47, 12), b512, 0, stream,
                           Th, Tl, BThi + (size_t)i * 98304, BTlo + (size_t)i * 98304,
                           (const float*)nullptr, TR, NN, 768);
        hipLaunchKernelGGL(k_conv_edge, dim3(6000), b256, 0, stream, TR, ei, eattr, AGG);
        hipLaunchKernelGGL(k_combine, dim3(3000), b256, 0, stream,
                           TR, AGG, HIN, nn_bias + i * 128, H);
    }

    hipLaunchKernelGGL(k_final, dim3(1500), b256, 0, stream,
                       H, dec_g, dec_b, out_w, out_b, out);
}

// Round 3
// 394.923 us; speedup vs baseline: 1.8109x; 1.2094x over previous
//
#include <hip/hip_runtime.h>
#include <math.h>

#define NN 6000
#define NE 12000
#define MAXD 64
// HC=128, H=4, D=32

typedef __bf16 bf16x8 __attribute__((ext_vector_type(8)));
typedef unsigned short u16x8 __attribute__((ext_vector_type(8)));
typedef float f32x4 __attribute__((ext_vector_type(4)));

__device__ __forceinline__ float gelu_f(float x) {
    return 0.5f * x * (1.0f + erff(x * 0.70710678118654752f));
}

__device__ __forceinline__ unsigned short bf16_rne(float x) {
    unsigned int u = __float_as_uint(x);
    unsigned int r = u + 0x7FFFu + ((u >> 16) & 1u);
    return (unsigned short)(r >> 16);
}
__device__ __forceinline__ float bf16_to_f(unsigned short h) {
    return __uint_as_float(((unsigned int)h) << 16);
}
__device__ __forceinline__ void split2(float x, unsigned short& hi, unsigned short& lo) {
    hi = bf16_rne(x);
    lo = bf16_rne(x - bf16_to_f(hi));
}

// ---------------- precompute: Bmat[i][k][768] = [M0|M1|M2|M3|M4|root] ----------------
__global__ __launch_bounds__(256) void k_pre_bmat(
    const float* __restrict__ nn_w, const float* __restrict__ nn_b,
    const float* __restrict__ nn_root,
    const float* __restrict__ eew, const float* __restrict__ eeb,
    float* __restrict__ Bmat)
{
    __shared__ float enc[5][128];
    int tid = threadIdx.x;
    for (int l = tid; l < 640; l += 256) {
        int j = l >> 7, k = l & 127;
        enc[j][k] = (j < 4) ? eew[j * 128 + k] : eeb[k];
    }
    __syncthreads();
    int gid = blockIdx.x * 256 + tid;       // 8 * 16384 total
    int i = gid >> 14;
    int col = gid & 16383;                  // k_in*128 + o
    int k_in = col >> 7, o = col & 127;
    const float* w = nn_w + (size_t)i * (128 * 16384) + col;
    float a0 = 0.f, a1 = 0.f, a2 = 0.f, a3 = 0.f, a4 = 0.f;
    #pragma unroll 8
    for (int k = 0; k < 128; ++k) {
        float wv = w[(size_t)k * 16384];
        a0 += enc[0][k] * wv; a1 += enc[1][k] * wv; a2 += enc[2][k] * wv;
        a3 += enc[3][k] * wv; a4 += enc[4][k] * wv;
    }
    a4 += nn_b[i * 16384 + col];
    float* brow = Bmat + (size_t)(i * 128 + k_in) * 768;
    brow[0 * 128 + o] = a0; brow[1 * 128 + o] = a1; brow[2 * 128 + o] = a2;
    brow[3 * 128 + o] = a3; brow[4 * 128 + o] = a4;
    brow[640 + o] = nn_root[i * 16384 + col];
}

// transpose + bf16 hi/lo split: src f32 [nmat][128][P] -> dst [nmat(dstride)][P][128]
__global__ __launch_bounds__(256) void k_split_t(
    const float* __restrict__ src, size_t mat_stride, int P,
    unsigned short* __restrict__ dhi, unsigned short* __restrict__ dlo,
    size_t dst_mat_stride)
{
    __shared__ float tile[128][129];
    int i = blockIdx.x, nb = blockIdx.y, tid = threadIdx.x;
    const float* s = src + (size_t)i * mat_stride + nb * 128;
    for (int l = tid; l < 128 * 128; l += 256) {
        int k = l >> 7, n = l & 127;
        tile[k][n] = s[(size_t)k * P + n];
    }
    __syncthreads();
    size_t dbase = (size_t)i * dst_mat_stride + (size_t)nb * 128 * 128;
    for (int l = tid; l < 128 * 128; l += 256) {
        int n = l >> 7, k = l & 127;
        float v = tile[k][n];
        unsigned short hi, lo; split2(v, hi, lo);
        dhi[dbase + (size_t)n * 128 + k] = hi;
        dlo[dbase + (size_t)n * 128 + k] = lo;
    }
}

// EW[i][j][o] (1280) then biasLR[2][256] (512)
__global__ void k_pre_ew(const float* __restrict__ gat_e_w,
    const float* __restrict__ eew, const float* __restrict__ eeb,
    const float* __restrict__ lb, const float* __restrict__ rb,
    float* __restrict__ EW, float* __restrict__ biasLR)
{
    int idx = blockIdx.x * 256 + threadIdx.x;
    if (idx < 1280) {
        int i = idx / 640; int r = idx % 640; int j = r >> 7; int o = r & 127;
        float s = 0.f;
        for (int k = 0; k < 128; ++k) {
            float e = (j < 4) ? eew[j * 128 + k] : eeb[k];
            s += e * gat_e_w[i * 16384 + k * 128 + o];
        }
        EW[idx] = s;
    } else if (idx < 1792) {
        int j = idx - 1280; int i = j >> 8; int c = j & 255;
        biasLR[j] = (c < 128) ? lb[i * 128 + c] : rb[i * 128 + c - 128];
    }
}

__global__ void k_node_enc(const float* __restrict__ x,
    const float* __restrict__ w, float* __restrict__ h0,
    unsigned short* __restrict__ hh, unsigned short* __restrict__ hl,
    int* __restrict__ cnt)
{
    int idx = blockIdx.x * 256 + threadIdx.x;   // N*128
    int n = idx >> 7, c = idx & 127;
    float s = 0.f;
    #pragma unroll
    for (int f = 0; f < 6; ++f) s += x[n * 6 + f] * w[f * 128 + c];
    h0[idx] = s;
    unsigned short hi, lo; split2(s, hi, lo);
    hh[idx] = hi; hl[idx] = lo;
    if (c == 0) cnt[n] = 0;
}

// ---------------- CSR build ----------------
__global__ void k_csr_count(const int* __restrict__ ei, int* __restrict__ cnt)
{
    int e = blockIdx.x * 256 + threadIdx.x;
    if (e < NE) atomicAdd(&cnt[ei[NE + e]], 1);
}

__global__ __launch_bounds__(1024) void k_csr_scan(
    const int* __restrict__ cnt, int* __restrict__ offs, int* __restrict__ cursor)
{
    __shared__ int carry;
    __shared__ int wsum[16];
    int tid = threadIdx.x, lane = tid & 63, w = tid >> 6;
    if (tid == 0) { carry = 0; offs[0] = 0; }
    __syncthreads();
    for (int base = 0; base < NN; base += 1024) {
        int i = base + tid;
        int v = (i < NN) ? cnt[i] : 0;
        int x = v;
        for (int o = 1; o < 64; o <<= 1) {
            int y = __shfl_up(x, o, 64);
            if (lane >= o) x += y;
        }
        if (lane == 63) wsum[w] = x;
        __syncthreads();
        if (tid == 0) {
            int a = 0;
            for (int w2 = 0; w2 < 16; ++w2) { int t = wsum[w2]; wsum[w2] = a; a += t; }
        }
        __syncthreads();
        int incl = x + wsum[w] + carry;
        if (i < NN) { offs[i + 1] = incl; cursor[i] = incl - v; }
        __syncthreads();
        if (tid == 1023) carry = incl;
        __syncthreads();
    }
}

__global__ void k_csr_scatter(const int* __restrict__ ei,
    int* __restrict__ cursor, int* __restrict__ eidx)
{
    int e = blockIdx.x * 256 + threadIdx.x;
    if (e < NE) {
        int d = ei[NE + e];
        int pos = atomicAdd(&cursor[d], 1);
        eidx[pos] = e;
    }
}

// ---------------- MFMA matmul 64x64 tile, 256 thr ----------------
// C[M,P] f32 = (Ahi+Alo) @ (Bhi+Blo)^T(stored [P][128]) + bias; bf16x3 passes.
__global__ __launch_bounds__(256) void k_mm_mfma(
    const unsigned short* __restrict__ Ah, const unsigned short* __restrict__ Al,
    const unsigned short* __restrict__ Bh, const unsigned short* __restrict__ Bl,
    const float* __restrict__ bias, float* __restrict__ C, int M, int P)
{
    __shared__ unsigned short sAh[64 * 128];
    __shared__ unsigned short sAl[64 * 128];
    __shared__ unsigned short sBh[64 * 128];
    __shared__ unsigned short sBl[64 * 128];
    const int tid = threadIdx.x;
    const int r0 = blockIdx.x * 64, n0 = blockIdx.y * 64;
    #pragma unroll
    for (int i = 0; i < 4; ++i) {
        int g = tid + i * 256; int row = g >> 4, u = g & 15;
        int dst = row * 128 + ((u ^ (row & 7)) << 3);
        int r = r0 + row;
        if (r < M) {
            *(u16x8*)&sAh[dst] = *(const u16x8*)&Ah[(size_t)r * 128 + u * 8];
            *(u16x8*)&sAl[dst] = *(const u16x8*)&Al[(size_t)r * 128 + u * 8];
        } else {
            u16x8 z; for (int j = 0; j < 8; ++j) z[j] = 0;
            *(u16x8*)&sAh[dst] = z; *(u16x8*)&sAl[dst] = z;
        }
        size_t sb = (size_t)(n0 + row) * 128 + u * 8;
        *(u16x8*)&sBh[dst] = *(const u16x8*)&Bh[sb];
        *(u16x8*)&sBl[dst] = *(const u16x8*)&Bl[sb];
    }
    __syncthreads();
    const int lane = tid & 63, wid = tid >> 6;
    const int wm = wid & 1, wn = wid >> 1;       // 2x2 wave grid of 32x32
    const int l15 = lane & 15, lg = lane >> 4;
    f32x4 acc[2][2] = {};
    #pragma unroll
    for (int kk = 0; kk < 4; ++kk) {
        u16x8 ah[2], al[2], bh[2], bl[2];
        #pragma unroll
        for (int fm = 0; fm < 2; ++fm) {
            int row = wm * 32 + fm * 16 + l15;
            int off = row * 128 + ((((kk << 2) + lg) ^ (row & 7)) << 3);
            ah[fm] = *(const u16x8*)&sAh[off];
            al[fm] = *(const u16x8*)&sAl[off];
        }
        #pragma unroll
        for (int fn = 0; fn < 2; ++fn) {
            int row = wn * 32 + fn * 16 + l15;
            int off = row * 128 + ((((kk << 2) + lg) ^ (row & 7)) << 3);
            bh[fn] = *(const u16x8*)&sBh[off];
            bl[fn] = *(const u16x8*)&sBl[off];
        }
        #pragma unroll
        for (int fm = 0; fm < 2; ++fm)
        #pragma unroll
        for (int fn = 0; fn < 2; ++fn) {
            acc[fm][fn] = __builtin_amdgcn_mfma_f32_16x16x32_bf16(
                __builtin_bit_cast(bf16x8, ah[fm]), __builtin_bit_cast(bf16x8, bh[fn]),
                acc[fm][fn], 0, 0, 0);
            acc[fm][fn] = __builtin_amdgcn_mfma_f32_16x16x32_bf16(
                __builtin_bit_cast(bf16x8, ah[fm]), __builtin_bit_cast(bf16x8, bl[fn]),
                acc[fm][fn], 0, 0, 0);
            acc[fm][fn] = __builtin_amdgcn_mfma_f32_16x16x32_bf16(
                __builtin_bit_cast(bf16x8, al[fm]), __builtin_bit_cast(bf16x8, bh[fn]),
                acc[fm][fn], 0, 0, 0);
        }
    }
    #pragma unroll
    for (int fn = 0; fn < 2; ++fn) {
        int col = n0 + wn * 32 + fn * 16 + l15;
        float bv = bias ? bias[col] : 0.f;
        #pragma unroll
        for (int fm = 0; fm < 2; ++fm) {
            int rbase = r0 + wm * 32 + fm * 16 + lg * 4;
            #pragma unroll
            for (int j = 0; j < 4; ++j) {
                int r = rbase + j;
                if (r < M) C[(size_t)r * P + col] = acc[fm][fn][j] + bv;
            }
        }
    }
}

// ---------------- fused GATv2 layer (per-dst CSR): softmax-agg + bias + LN + gelu + split ----------------
__global__ __launch_bounds__(256) void k_gat_fused(
    const float* __restrict__ XLXR, const int* __restrict__ ei,
    const float* __restrict__ eattr, const int* __restrict__ offs,
    const int* __restrict__ eidx, const float* __restrict__ EW,
    const float* __restrict__ att, float* __restrict__ h0,
    const float* __restrict__ bias, const float* __restrict__ g,
    const float* __restrict__ b,
    unsigned short* __restrict__ hh, unsigned short* __restrict__ hl)
{
    __shared__ float slog[4][MAXD][4];
    __shared__ float sms[4][4][2];
    int rowl = threadIdx.x >> 6, lane = threadIdx.x & 63;
    int r = blockIdx.x * 4 + rowl;
    int o0 = offs[r], deg = offs[r + 1] - o0;
    if (deg > MAXD) deg = MAXD;
    float xr0 = XLXR[r * 256 + 128 + lane];
    float xr1 = XLXR[r * 256 + 192 + lane];
    float e0 = EW[lane], e1 = EW[128 + lane], e2 = EW[256 + lane], e3 = EW[384 + lane], e4 = EW[512 + lane];
    float f0 = EW[64 + lane], f1 = EW[192 + lane], f2 = EW[320 + lane], f3 = EW[448 + lane], f4 = EW[576 + lane];
    float at0 = att[lane], at1 = att[64 + lane];
    for (int k = 0; k < deg; ++k) {
        int e = eidx[o0 + k]; int s = ei[e];
        float a0 = eattr[e * 4 + 0], a1 = eattr[e * 4 + 1];
        float a2 = eattr[e * 4 + 2], a3 = eattr[e * 4 + 3];
        float g0 = XLXR[s * 256 + lane]      + xr0 + (a0 * e0 + a1 * e1 + a2 * e2 + a3 * e3 + e4);
        float g1 = XLXR[s * 256 + 64 + lane] + xr1 + (a0 * f0 + a1 * f1 + a2 * f2 + a3 * f3 + f4);
        g0 = (g0 > 0.f) ? g0 : 0.1f * g0;
        g1 = (g1 > 0.f) ? g1 : 0.1f * g1;
        float p0 = g0 * at0, p1 = g1 * at1;
        for (int o = 16; o; o >>= 1) { p0 += __shfl_xor(p0, o, 32); p1 += __shfl_xor(p1, o, 32); }
        if ((lane & 31) == 0) {
            int hh2 = lane >> 5;                 // 0 or 1
            slog[rowl][k][hh2] = p0;             // heads 0/1
            slog[rowl][k][2 + hh2] = p1;         // heads 2/3
        }
    }
    // per-head max & sum (lanes 0..3, wave-lockstep)
    if (lane < 4) {
        float mh = -1e30f;
        for (int k = 0; k < deg; ++k) mh = fmaxf(mh, slog[rowl][k][lane]);
        float sh = 0.f;
        for (int k = 0; k < deg; ++k) sh += expf(slog[rowl][k][lane] - mh);
        sms[rowl][lane][0] = mh; sms[rowl][lane][1] = sh;
    }
    int hd = lane >> 5;
    float m0 = sms[rowl][hd][0], s0 = sms[rowl][hd][1];
    float m1 = sms[rowl][2 + hd][0], s1 = sms[rowl][2 + hd][1];
    float acc0 = 0.f, acc1 = 0.f;
    for (int k = 0; k < deg; ++k) {
        int e = eidx[o0 + k]; int s = ei[e];
        float al0 = expf(slog[rowl][k][hd] - m0) / (s0 + 1e-16f);
        float al1 = expf(slog[rowl][k][2 + hd] - m1) / (s1 + 1e-16f);
        acc0 += al0 * XLXR[s * 256 + lane];
        acc1 += al1 * XLXR[s * 256 + 64 + lane];
    }
    float v0 = h0[r * 128 + lane]      + acc0 + bias[lane];
    float v1 = h0[r * 128 + 64 + lane] + acc1 + bias[64 + lane];
    float sum = v0 + v1;
    for (int o = 32; o; o >>= 1) sum += __shfl_xor(sum, o, 64);
    float mean = sum * 0.0078125f;
    float d0 = v0 - mean, d1 = v1 - mean;
    float var = d0 * d0 + d1 * d1;
    for (int o = 32; o; o >>= 1) var += __shfl_xor(var, o, 64);
    float inv = rsqrtf(var * 0.0078125f + 1e-5f);
    float y0 = gelu_f(d0 * inv * g[lane] + b[lane]);
    float y1 = gelu_f(d1 * inv * g[64 + lane] + b[64 + lane]);
    h0[r * 128 + lane] = y0; h0[r * 128 + 64 + lane] = y1;
    unsigned short hi, lo;
    split2(y0, hi, lo); hh[r * 128 + lane] = hi;      hl[r * 128 + lane] = lo;
    split2(y1, hi, lo); hh[r * 128 + 64 + lane] = hi; hl[r * 128 + 64 + lane] = lo;
}

// ---------------- fused NNConv (per-dst CSR): agg + root + bias (+hin) -> H; then next-LN -> T (or final projection)
__global__ __launch_bounds__(256) void k_conv_fused(
    const float* __restrict__ TR, const int* __restrict__ ei,
    const float* __restrict__ eattr, const int* __restrict__ offs,
    const int* __restrict__ eidx,
    const float* __restrict__ Hprev,     // null for initial conv
    const float* __restrict__ h0,
    const float* __restrict__ bias,
    float* __restrict__ Hout,
    const float* __restrict__ lng, const float* __restrict__ lnb,
    unsigned short* __restrict__ th, unsigned short* __restrict__ tl,
    int final_mode,
    const float* __restrict__ outw, const float* __restrict__ outb,
    float* __restrict__ out)
{
    int rowl = threadIdx.x >> 6, lane = threadIdx.x & 63;
    int r = blockIdx.x * 4 + rowl;
    int o0 = offs[r], deg = offs[r + 1] - o0;
    float acc0 = 0.f, acc1 = 0.f;
    for (int k = 0; k < deg; ++k) {
        int e = eidx[o0 + k]; int s = ei[e];
        float a0 = eattr[e * 4 + 0], a1 = eattr[e * 4 + 1];
        float a2 = eattr[e * 4 + 2], a3 = eattr[e * 4 + 3];
        const float* t = TR + (size_t)s * 768;
        acc0 += a0 * t[lane]      + a1 * t[128 + lane] + a2 * t[256 + lane]
              + a3 * t[384 + lane] + t[512 + lane];
        acc1 += a0 * t[64 + lane] + a1 * t[192 + lane] + a2 * t[320 + lane]
              + a3 * t[448 + lane] + t[576 + lane];
    }
    const float* td = TR + (size_t)r * 768 + 640;
    float v0 = acc0 + td[lane]      + bias[lane];
    float v1 = acc1 + td[64 + lane] + bias[64 + lane];
    if (Hprev) {
        v0 += h0[r * 128 + lane]      + Hprev[r * 128 + lane];
        v1 += h0[r * 128 + 64 + lane] + Hprev[r * 128 + 64 + lane];
    }
    Hout[r * 128 + lane] = v0; Hout[r * 128 + 64 + lane] = v1;
    float u0, u1;
    if (!final_mode) { u0 = h0[r * 128 + lane] + v0; u1 = h0[r * 128 + 64 + lane] + v1; }
    else             { u0 = v0; u1 = v1; }
    float sum = u0 + u1;
    for (int o = 32; o; o >>= 1) sum += __shfl_xor(sum, o, 64);
    float mean = sum * 0.0078125f;
    float d0 = u0 - mean, d1 = u1 - mean;
    float var = d0 * d0 + d1 * d1;
    for (int o = 32; o; o >>= 1) var += __shfl_xor(var, o, 64);
    float inv = rsqrtf(var * 0.0078125f + 1e-5f);
    float y0 = gelu_f(d0 * inv * lng[lane] + lnb[lane]);
    float y1 = gelu_f(d1 * inv * lng[64 + lane] + lnb[64 + lane]);
    if (!final_mode) {
        unsigned short hi, lo;
        split2(y0, hi, lo); th[r * 128 + lane] = hi;      tl[r * 128 + lane] = lo;
        split2(y1, hi, lo); th[r * 128 + 64 + lane] = hi; tl[r * 128 + 64 + lane] = lo;
    } else {
        float p0 = y0 * outw[lane * 2 + 0] + y1 * outw[(64 + lane) * 2 + 0];
        float p1 = y0 * outw[lane * 2 + 1] + y1 * outw[(64 + lane) * 2 + 1];
        for (int o = 32; o; o >>= 1) { p0 += __shfl_xor(p0, o, 64); p1 += __shfl_xor(p1, o, 64); }
        if (lane == 0) {
            out[r * 2 + 0] = p0 + outb[0];
            out[r * 2 + 1] = p1 + outb[1];
        }
    }
}

extern "C" void kernel_launch(void* const* d_in, const int* in_sizes, int n_in,
                              void* d_out, int out_size, void* d_ws, size_t ws_size,
                              hipStream_t stream)
{
    const float* x        = (const float*)d_in[0];
    const int*   ei       = (const int*)d_in[1];
    const float* eattr    = (const float*)d_in[2];
    const float* node_w   = (const float*)d_in[4];
    const float* eew      = (const float*)d_in[5];
    const float* eeb      = (const float*)d_in[6];
    const float* gat_l_w  = (const float*)d_in[7];
    const float* gat_l_b  = (const float*)d_in[8];
    const float* gat_r_w  = (const float*)d_in[9];
    const float* gat_r_b  = (const float*)d_in[10];
    const float* gat_e_w  = (const float*)d_in[11];
    const float* gat_att  = (const float*)d_in[12];
    const float* gat_bias = (const float*)d_in[13];
    const float* gat_ln_g = (const float*)d_in[14];
    const float* gat_ln_b = (const float*)d_in[15];
    const float* nn_w     = (const float*)d_in[16];
    const float* nn_b     = (const float*)d_in[17];
    const float* nn_root  = (const float*)d_in[18];
    const float* nn_bias  = (const float*)d_in[19];
    const float* dec_g    = (const float*)d_in[20];
    const float* dec_b    = (const float*)d_in[21];
    const float* out_w    = (const float*)d_in[22];
    const float* out_b    = (const float*)d_in[23];
    float* out = (float*)d_out;

    float* ws    = (float*)d_ws;
    float* BMAT  = ws;                    // 786432
    float* EW    = BMAT + 786432;         // 1280
    float* BLR   = EW + 1280;             // 512
    float* H0    = BLR + 512;             // 768000
    float* H     = H0 + 768000;           // 768000
    float* TR    = H + 768000;            // 4608000
    float* XLXR  = TR + 4608000;          // 1536000
    int*   CNT   = (int*)(XLXR + 1536000);    // 6000
    int*   OFFS  = CNT + 6000;                // 6001
    int*   CURS  = OFFS + 6001;               // 6000
    int*   EIDX  = CURS + 6000;               // 12000 (+pad to even)
    unsigned short* usbase = (unsigned short*)(EIDX + 12001);
    unsigned short* BThi = usbase;            // 8*768*128 = 786432
    unsigned short* BTlo = BThi + 786432;
    unsigned short* WThi = BTlo + 786432;     // 2 layers x 256 x 128 = 65536
    unsigned short* WTlo = WThi + 65536;
    unsigned short* H0h  = WTlo + 65536;      // 768000
    unsigned short* H0l  = H0h + 768000;
    unsigned short* Th   = H0l + 768000;
    unsigned short* Tl   = Th + 768000;

    dim3 b256(256);
    hipLaunchKernelGGL(k_pre_bmat, dim3(512), b256, 0, stream, nn_w, nn_b, nn_root, eew, eeb, BMAT);
    hipLaunchKernelGGL(k_split_t, dim3(8, 6), b256, 0, stream, BMAT, (size_t)98304, 768, BThi, BTlo, (size_t)98304);
    hipLaunchKernelGGL(k_split_t, dim3(2, 1), b256, 0, stream, gat_l_w, (size_t)16384, 128, WThi, WTlo, (size_t)32768);
    hipLaunchKernelGGL(k_split_t, dim3(2, 1), b256, 0, stream, gat_r_w, (size_t)16384, 128, WThi + 16384, WTlo + 16384, (size_t)32768);
    hipLaunchKernelGGL(k_pre_ew, dim3(7), b256, 0, stream, gat_e_w, eew, eeb, gat_l_b, gat_r_b, EW, BLR);
    hipLaunchKernelGGL(k_node_enc, dim3(3000), b256, 0, stream, x, node_w, H0, H0h, H0l, CNT);
    hipLaunchKernelGGL(k_csr_count, dim3(47), b256, 0, stream, ei, CNT);
    hipLaunchKernelGGL(k_csr_scan, dim3(1), dim3(1024), 0, stream, CNT, OFFS, CURS);
    hipLaunchKernelGGL(k_csr_scatter, dim3(47), b256, 0, stream, ei, CURS, EIDX);

    for (int i = 0; i < 2; ++i) {
        hipLaunchKernelGGL(k_mm_mfma, dim3(94, 4), b256, 0, stream,
                           H0h, H0l, WThi + i * 32768, WTlo + i * 32768,
                           BLR + i * 256, XLXR, NN, 256);
        hipLaunchKernelGGL(k_gat_fused, dim3(1500), b256, 0, stream,
                           XLXR, ei, eattr, OFFS, EIDX, EW + i * 640, gat_att + i * 128,
                           H0, gat_bias + i * 128, gat_ln_g + i * 128, gat_ln_b + i * 128,
                           H0h, H0l);
    }

    // initial conv (uses nn layer 0), then 8 res+ layers; last fused does final LN+projection
    hipLaunchKernelGGL(k_mm_mfma, dim3(94, 12), b256, 0, stream,
                       H0h, H0l, BThi, BTlo, (const float*)nullptr, TR, NN, 768);
    hipLaunchKernelGGL(k_conv_fused, dim3(1500), b256, 0, stream,
                       TR, ei, eattr, OFFS, EIDX, (const float*)nullptr, H0,
                       nn_bias, H, dec_g, dec_b, Th, Tl, 0,
                       (const float*)nullptr, (const float*)nullptr, (float*)nullptr);

    for (int i = 0; i < 8; ++i) {
        hipLaunchKernelGGL(k_mm_mfma, dim3(94, 12), b256, 0, stream,
                           Th, Tl, BThi + (size_t)i * 98304, BTlo + (size_t)i * 98304,
                           (const float*)nullptr, TR, NN, 768);
        int fin = (i == 7);
        hipLaunchKernelGGL(k_conv_fused, dim3(1500), b256, 0, stream,
                           TR, ei, eattr, OFFS, EIDX, H, H0,
                           nn_bias + i * 128, H,
                           fin ? dec_g : dec_g + (i + 1) * 128,
                           fin ? dec_b : dec_b + (i + 1) * 128,
                           Th, Tl, fin, out_w, out_b, out);
    }
}